// Round 3
// baseline (37692.172 us; speedup 1.0000x reference)
//
#include <hip/hip_runtime.h>
#include <math.h>

#define TT 2048
#define BB 32
#define DD 512
#define GB 8           // batch groups (4 batches each)
#define GS 32          // slices per group (16 hidden units each)
#define NBLK (GB*GS)   // 256 blocks = 1 per CU -> co-residency guaranteed
#define NTHR 512
#define BPG (BB/GB)    // 4 batches per group
#define HU 16
#define ROWS 64        // h elements per block written to out (64 of group's 2048)
#define CHP 68         // padded chunk stride (68%32=4, 272B keeps 16B alignment)
#define NW 8           // waves per block

// Coherence-point (MALL) accessors: agent-scope relaxed atomics compile to
// global_load/store ... sc0 sc1 (bypass L1 + non-coherent per-XCD L2). Round 2
// showed 64-bit tag-in-payload polling amplifies HBM write traffic 40x; this
// version polls small 32-bit FLAG words only (round-1 scheme, proven cheap).
__device__ __forceinline__ unsigned ld_mall32(const unsigned* p) {
  return __hip_atomic_load((unsigned*)p, __ATOMIC_RELAXED, __HIP_MEMORY_SCOPE_AGENT);
}
__device__ __forceinline__ void st_mall32(unsigned* p, unsigned v) {
  __hip_atomic_store(p, v, __ATOMIC_RELAXED, __HIP_MEMORY_SCOPE_AGENT);
}
__device__ __forceinline__ float sigm(float v) {
  return __builtin_amdgcn_rcpf(1.0f + __expf(-v));
}
__device__ __forceinline__ float tanh_fast(float v) {
  return 2.0f * sigm(2.0f * v) - 1.0f;   // exact identity tanh(x)=2*sigmoid(2x)-1
}

// Persistent LSTM. 256 blocks x 512 threads, 1 block/CU. Per thread: 2 gate rows
// x (32-wide Wih chunk + 32-wide Whh chunk) in VGPRs. Row mapping puts (i,g) and
// (f,o) rows of a unit in lanes tid^16 of the SAME wave -> in-wave cell update
// (no gates LDS, no 3rd barrier), cell state in registers. Per step:
//   stage x(t) (prefetched) | barrier A | x-dot (overlaps producers' publish)
//   per-thread poll of per-wave flags -> stage h(t-1) | barrier B
//   h-dot + kc-reduce + shfl(16) gather -> cell update -> h stores
//   s_waitcnt vmcnt(0) (wave-scoped) -> per-wave flag publish.
__global__ __launch_bounds__(NTHR, 2)
void lstm_persistent(const float* __restrict__ x,
                     const float* __restrict__ Wih,
                     const float* __restrict__ Whh,
                     const float* __restrict__ bih,
                     const float* __restrict__ bhh,
                     float* __restrict__ out,
                     float* __restrict__ Hglob,       // [GB][2][BPG][DD] f32
                     unsigned* __restrict__ flags)    // [GB][GS][NW] step counters
{
  __shared__ float in_buf[BPG][16][CHP];   // [batch][row][64+pad]; rows 0-7 = x, 8-15 = h

  const int tid = threadIdx.x;
  const int blk = blockIdx.x;
  const int g   = blk & 7;    // group (blk%8 -> same XCD under round-robin; perf only)
  const int s   = blk >> 3;   // slice 0..31
  const int j   = tid >> 4;   // 0..31 row-pair id
  const int kc  = tid & 15;   // 0..15 k-chunk (32 floats each, per weight half)
  const int u0  = s * HU;
  const int gb0 = g * BPG;
  const int v   = j >> 1;     // hidden unit 0..15 within slice (unit = wave's 2w + lane>=32)
  const int gl  = j & 1;      // 0: rows (i,g)   1: rows (f,o)
  const int row0 = gl * DD + u0 + v;        // gate i or f
  const int row1 = (gl + 2) * DD + u0 + v;  // gate g or o

  // --- per-thread weights: 2 rows x 32 floats from Wih + 32 floats from Whh ---
  float4 w0x[8], w1x[8], w0h[8], w1h[8];
  {
    const float4* p0x = (const float4*)(Wih + (size_t)row0 * DD + kc * 32);
    const float4* p1x = (const float4*)(Wih + (size_t)row1 * DD + kc * 32);
    const float4* p0h = (const float4*)(Whh + (size_t)row0 * DD + kc * 32);
    const float4* p1h = (const float4*)(Whh + (size_t)row1 * DD + kc * 32);
    #pragma unroll
    for (int q = 0; q < 8; ++q) {
      w0x[q] = p0x[q]; w1x[q] = p1x[q]; w0h[q] = p0h[q]; w1h[q] = p1h[q];
    }
  }
  // biases for the 4 gates of this lane's unit v
  const float b_i = bih[0*DD + u0 + v] + bhh[0*DD + u0 + v];
  const float b_f = bih[1*DD + u0 + v] + bhh[1*DD + u0 + v];
  const float b_g = bih[2*DD + u0 + v] + bhh[2*DD + u0 + v];
  const float b_o = bih[3*DD + u0 + v] + bhh[3*DD + u0 + v];

  float c_st[BPG] = {0.f, 0.f, 0.f, 0.f};   // cell state, replicated across lanes

  const int sb   = tid >> 7;            // staging batch 0..3
  const int kpos = (tid & 127) * 4;     // staging position 0..508
  // flags for the producer wave pair covering units kpos..kpos+3:
  // slice kpos>>4, local units (kpos&15)..+3 -> waves ((kpos&15)>>1), +1
  const unsigned* myflags = flags + ((size_t)g * GS + (kpos >> 4)) * NW + ((kpos & 15) >> 1);
  const float* xg = x + (size_t)(gb0 + sb) * TT * DD + kpos;
  float4 vx = *(const float4*)xg;       // x(0) prefetched

  for (int t = 0; t < TT; ++t) {
    // --- stage x(t) (prefetched last iter); prefetch x(t+1).
    // Writes rows 0-7 only; step t-1 readers of rows 8-15 are unaffected. ---
    *(float4*)&in_buf[sb][kpos >> 6][kpos & 63] = vx;
    {
      int tn = (t + 1 < TT) ? t + 1 : t;   // clamp avoids OOB on last step
      vx = *(const float4*)(xg + (size_t)tn * DD);
    }
    __syncthreads();   // A: x staged; all step-(t-1) LDS reads complete

    // --- x-part dots (h-independent; overlaps producers' publish latency) ---
    float rx0[BPG], rx1[BPG];
    #pragma unroll
    for (int b = 0; b < BPG; ++b) {
      const float4* vp = (const float4*)&in_buf[b][kc >> 1][(kc & 1) * 32];
      float4 a0 = {0,0,0,0}, a1 = {0,0,0,0};
      #pragma unroll
      for (int q = 0; q < 8; ++q) {
        float4 vv = vp[q];
        a0.x += vv.x * w0x[q].x; a0.y += vv.y * w0x[q].y;
        a0.z += vv.z * w0x[q].z; a0.w += vv.w * w0x[q].w;
        a1.x += vv.x * w1x[q].x; a1.y += vv.y * w1x[q].y;
        a1.z += vv.z * w1x[q].z; a1.w += vv.w * w1x[q].w;
      }
      rx0[b] = (a0.x + a0.y) + (a0.z + a0.w);
      rx1[b] = (a1.x + a1.y) + (a1.z + a1.w);
    }

    // --- per-thread poll of the two producer-wave flags, then stage h(t-1) ---
    if (t == 0) {
      float4 z = {0, 0, 0, 0};
      *(float4*)&in_buf[sb][8 + (kpos >> 6)][kpos & 63] = z;
    } else {
      const unsigned tt = (unsigned)t;
      int guard = 0;
      while (ld_mall32(myflags) < tt || ld_mall32(myflags + 1) < tt) {
        if (++guard > (1 << 22)) break;   // fail loud-ish, never hang the harness
        __builtin_amdgcn_s_sleep(2);
      }
      const float* hsrc = Hglob + ((size_t)(g * 2 + ((t - 1) & 1)) * BPG + sb) * DD + kpos;
      float4 hv;
      hv.x = __uint_as_float(ld_mall32((const unsigned*)hsrc + 0));
      hv.y = __uint_as_float(ld_mall32((const unsigned*)hsrc + 1));
      hv.z = __uint_as_float(ld_mall32((const unsigned*)hsrc + 2));
      hv.w = __uint_as_float(ld_mall32((const unsigned*)hsrc + 3));
      *(float4*)&in_buf[sb][8 + (kpos >> 6)][kpos & 63] = hv;
    }
    __syncthreads();   // B: h staged

    // --- write h(t-1) to out from the staged copy (off critical path, wave 0) ---
    if (t > 0 && tid < ROWS) {
      int flat = s * 64 + tid;           // partition of group's [BPG][DD]
      int ob = flat >> 9, okp = flat & 511;
      out[((size_t)(gb0 + ob) * TT + (t - 1)) * DD + okp] =
          in_buf[ob][8 + (okp >> 6)][okp & 63];
    }

    // --- h-part dots + combine with x-part ---
    float r0[BPG], r1[BPG];
    #pragma unroll
    for (int b = 0; b < BPG; ++b) {
      const float4* vp = (const float4*)&in_buf[b][8 + (kc >> 1)][(kc & 1) * 32];
      float4 a0 = {0,0,0,0}, a1 = {0,0,0,0};
      #pragma unroll
      for (int q = 0; q < 8; ++q) {
        float4 vv = vp[q];
        a0.x += vv.x * w0h[q].x; a0.y += vv.y * w0h[q].y;
        a0.z += vv.z * w0h[q].z; a0.w += vv.w * w0h[q].w;
        a1.x += vv.x * w1h[q].x; a1.y += vv.y * w1h[q].y;
        a1.z += vv.z * w1h[q].z; a1.w += vv.w * w1h[q].w;
      }
      r0[b] = rx0[b] + (a0.x + a0.y) + (a0.z + a0.w);
      r1[b] = rx1[b] + (a1.x + a1.y) + (a1.z + a1.w);
    }
    // reduce across the 16 kc lanes; all 4 batches interleaved for ILP
    #pragma unroll
    for (int m = 1; m < 16; m <<= 1) {
      #pragma unroll
      for (int b = 0; b < BPG; ++b) {
        r0[b] += __shfl_xor(r0[b], m, 64);
        r1[b] += __shfl_xor(r1[b], m, 64);
      }
    }

    // --- in-wave cell update: lanes tid^16 hold (f,o) for this lane's (i,g) ---
    float* hd = Hglob + (size_t)(g * 2 + (t & 1)) * BPG * DD + u0 + v;
    #pragma unroll
    for (int b = 0; b < BPG; ++b) {
      float f_in = __shfl_xor(r0[b], 16, 64);
      float o_in = __shfl_xor(r1[b], 16, 64);
      float ig = sigm(r0[b] + b_i);
      float fg = sigm(f_in + b_f);
      float gg = tanh_fast(r1[b] + b_g);
      float og = sigm(o_in + b_o);
      float c  = fg * c_st[b] + ig * gg;
      c_st[b] = c;
      float h  = og * tanh_fast(c);
      if ((tid & 31) == 0)   // owning lane for unit v (gl==0, kc==0)
        st_mall32((unsigned*)(hd + b * DD), __float_as_uint(h));
    }
    // Wave-scoped ordering: wait this wave's h stores (8: 2 units x 4 batches)
    // to reach the coherence point, then publish this wave's flag.
    asm volatile("s_waitcnt vmcnt(0)" ::: "memory");
    if ((tid & 63) == 0)
      st_mall32(&flags[((size_t)g * GS + s) * NW + (tid >> 6)], (unsigned)(t + 1));
    // No 3rd barrier: rows 0-7 rewritten next loop-top (disjoint from rows 8-15
    // still being read by other waves); rows 8-15 rewritten only after A(t+1).
  }

  // --- emit final timestep h(T-1) straight from Hglob ---
  if (tid < ROWS) {
    int flat = s * 64 + tid;
    int ob = flat >> 9, okp = flat & 511;
    const unsigned* fw = flags + ((size_t)g * GS + (okp >> 4)) * NW + ((okp & 15) >> 1);
    int guard = 0;
    while (ld_mall32(fw) < (unsigned)TT) {
      if (++guard > (1 << 22)) break;
      __builtin_amdgcn_s_sleep(2);
    }
    const unsigned* hsrc = (const unsigned*)Hglob
        + ((size_t)(g * 2 + ((TT - 1) & 1)) * BPG + ob) * DD + okp;
    out[((size_t)(gb0 + ob) * TT + (TT - 1)) * DD + okp] =
        __uint_as_float(ld_mall32(hsrc));
  }
}

extern "C" void kernel_launch(void* const* d_in, const int* in_sizes, int n_in,
                              void* d_out, int out_size, void* d_ws, size_t ws_size,
                              hipStream_t stream) {
  const float* x   = (const float*)d_in[0];
  const float* Wih = (const float*)d_in[1];
  const float* Whh = (const float*)d_in[2];
  const float* bih = (const float*)d_in[3];
  const float* bhh = (const float*)d_in[4];
  float* out = (float*)d_out;

  // ws layout: Hglob [8][2][4][512] f32 = 128 KB, then flags [8][32][8] u32 = 8 KB
  float* Hglob = (float*)d_ws;
  unsigned* flags = (unsigned*)((char*)d_ws + (size_t)GB * 2 * BPG * DD * sizeof(float));

  // ws is poisoned before every call: zero the flags before the kernel polls them.
  hipMemsetAsync(flags, 0, (size_t)GB * GS * NW * sizeof(unsigned), stream);

  lstm_persistent<<<dim3(NBLK), dim3(NTHR), 0, stream>>>(x, Wih, Whh, bih, bhh,
                                                         out, Hglob, flags);
}

// Round 4
// 16608.173 us; speedup vs baseline: 2.2695x; 2.2695x over previous
//
#include <hip/hip_runtime.h>
#include <math.h>

#define TT 2048
#define BB 32
#define DD 512
#define GB 8           // batch groups (4 batches each)
#define GS 32          // slices per group (16 hidden units each)
#define NBLK (GB*GS)   // 256 blocks = 1 per CU -> co-residency guaranteed
#define NTHR 512
#define BPG (BB/GB)    // 4 batches per group
#define HU 16
#define ROWS 64        // h elements per block written to out (64 of group's 2048)
#define CHP 68         // padded chunk stride (68%32=4, 272B keeps 16B alignment)

typedef float f32x4 __attribute__((ext_vector_type(4)));

// Coherence-point (MALL) accessors. Lesson from rounds 2+3: the count of
// SPINNING agent-scope load transactions is the dominant perf knob -> poll with
// 32 lanes x one 4B block-level flag (round-1 scheme, proven 165MB total fetch).
__device__ __forceinline__ unsigned ld_mall32(const unsigned* p) {
  return __hip_atomic_load((unsigned*)p, __ATOMIC_RELAXED, __HIP_MEMORY_SCOPE_AGENT);
}
__device__ __forceinline__ void st_mall32(unsigned* p, unsigned v) {
  __hip_atomic_store(p, v, __ATOMIC_RELAXED, __HIP_MEMORY_SCOPE_AGENT);
}
// One 16B MALL-bypass load (4x fewer transactions than 4 scalar agent loads).
__device__ __forceinline__ f32x4 ld_mall128(const float* p) {
  f32x4 r;
  asm volatile("global_load_dwordx4 %0, %1, off sc0 sc1\n\ts_waitcnt vmcnt(0)"
               : "=v"(r) : "v"(p) : "memory");
  return r;
}
__device__ __forceinline__ float sigm(float v) {
  return __builtin_amdgcn_rcpf(1.0f + __expf(-v));
}
__device__ __forceinline__ float tanh_fast(float v) {
  return 2.0f * sigm(2.0f * v) - 1.0f;   // exact identity tanh(x)=2*sigmoid(2x)-1
}

// Persistent LSTM. 256 blocks x 512 threads, 1 block/CU. Per thread: 2 gate rows
// x (32-wide Wih chunk + 32-wide Whh chunk) in VGPRs. Rows (i,g)/(f,o) of a unit
// live in lanes tid^16 of the SAME wave -> in-wave cell update, c in registers.
// Per step:
//   stage x(t) (reg-prefetched) | A | x-dot (overlaps producers' publish)
//   poll: 32 lanes x 1 block-flag | Bp | stage h(t-1) via dwordx4 sc0sc1 | B
//   h-dot + kc-reduce + shfl(16) gather -> cell update -> h stores
//   C (implicit vmcnt(0) drain per wave) -> tid0 publishes block flag
//   out-write h(t-1) AFTER publish (never gates the chain).
__global__ __launch_bounds__(NTHR, 2)
void lstm_persistent(const float* __restrict__ x,
                     const float* __restrict__ Wih,
                     const float* __restrict__ Whh,
                     const float* __restrict__ bih,
                     const float* __restrict__ bhh,
                     float* __restrict__ out,
                     float* __restrict__ Hglob,       // [GB][2][BPG][DD] f32
                     unsigned* __restrict__ flags)    // [GB][GS] step counters
{
  __shared__ float in_buf[BPG][16][CHP];   // [batch][row][64+pad]; rows 0-7 = x, 8-15 = h

  const int tid = threadIdx.x;
  const int blk = blockIdx.x;
  const int g   = blk & 7;    // group (blk%8 -> same XCD under round-robin; perf only)
  const int s   = blk >> 3;   // slice 0..31
  const int j   = tid >> 4;   // 0..31 row-pair id
  const int kc  = tid & 15;   // 0..15 k-chunk (32 floats each, per weight half)
  const int u0  = s * HU;
  const int gb0 = g * BPG;
  const int v   = j >> 1;     // hidden unit 0..15 within slice
  const int gl  = j & 1;      // 0: rows (i,g)   1: rows (f,o)
  const int row0 = gl * DD + u0 + v;        // gate i or f
  const int row1 = (gl + 2) * DD + u0 + v;  // gate g or o

  // --- per-thread weights: 2 rows x 32 floats from Wih + 32 floats from Whh ---
  float4 w0x[8], w1x[8], w0h[8], w1h[8];
  {
    const float4* p0x = (const float4*)(Wih + (size_t)row0 * DD + kc * 32);
    const float4* p1x = (const float4*)(Wih + (size_t)row1 * DD + kc * 32);
    const float4* p0h = (const float4*)(Whh + (size_t)row0 * DD + kc * 32);
    const float4* p1h = (const float4*)(Whh + (size_t)row1 * DD + kc * 32);
    #pragma unroll
    for (int q = 0; q < 8; ++q) {
      w0x[q] = p0x[q]; w1x[q] = p1x[q]; w0h[q] = p0h[q]; w1h[q] = p1h[q];
    }
  }
  // biases for the 4 gates of this lane's unit v
  const float b_i = bih[0*DD + u0 + v] + bhh[0*DD + u0 + v];
  const float b_f = bih[1*DD + u0 + v] + bhh[1*DD + u0 + v];
  const float b_g = bih[2*DD + u0 + v] + bhh[2*DD + u0 + v];
  const float b_o = bih[3*DD + u0 + v] + bhh[3*DD + u0 + v];

  float c_st[BPG] = {0.f, 0.f, 0.f, 0.f};   // cell state, replicated across lanes

  const int sb   = tid >> 7;            // staging batch 0..3
  const int kpos = (tid & 127) * 4;     // staging position 0..508
  const float* xg = x + (size_t)(gb0 + sb) * TT * DD + kpos;
  float4 vx = *(const float4*)xg;       // x(0) prefetched

  for (int t = 0; t < TT; ++t) {
    // --- stage x(t) (prefetched last iter); prefetch x(t+1).
    // Rows 0-7 are dead since B(t-1): all x-dot reads finished before it. ---
    *(float4*)&in_buf[sb][kpos >> 6][kpos & 63] = vx;
    {
      int tn = (t + 1 < TT) ? t + 1 : t;   // clamp avoids OOB on last step
      vx = *(const float4*)(xg + (size_t)tn * DD);
    }
    __syncthreads();   // A: x staged; step-(t-1) h-dot reads of rows 8-15 complete

    // --- x-part dots (h-independent; overlaps producers' publish latency) ---
    float rx0[BPG], rx1[BPG];
    #pragma unroll
    for (int b = 0; b < BPG; ++b) {
      const float4* vp = (const float4*)&in_buf[b][kc >> 1][(kc & 1) * 32];
      float4 a0 = {0,0,0,0}, a1 = {0,0,0,0};
      #pragma unroll
      for (int q = 0; q < 8; ++q) {
        float4 vv = vp[q];
        a0.x += vv.x * w0x[q].x; a0.y += vv.y * w0x[q].y;
        a0.z += vv.z * w0x[q].z; a0.w += vv.w * w0x[q].w;
        a1.x += vv.x * w1x[q].x; a1.y += vv.y * w1x[q].y;
        a1.z += vv.z * w1x[q].z; a1.w += vv.w * w1x[q].w;
      }
      rx0[b] = (a0.x + a0.y) + (a0.z + a0.w);
      rx1[b] = (a1.x + a1.y) + (a1.z + a1.w);
    }

    // --- poll: 32 lanes, one 4B block-level flag each (minimal MALL traffic) ---
    if (t > 0) {
      if (tid < GS) {
        const unsigned tt = (unsigned)t;
        int guard = 0;
        while (ld_mall32(&flags[g * GS + tid]) < tt) {
          if (++guard > (1 << 24)) break;   // fail loud-ish, never hang the harness
          __builtin_amdgcn_s_sleep(1);
        }
      }
      __syncthreads();   // Bp: all producer blocks' h published
    }

    // --- stage h(t-1): one dwordx4 sc0sc1 per thread ---
    if (t == 0) {
      float4 z = {0, 0, 0, 0};
      *(float4*)&in_buf[sb][8 + (kpos >> 6)][kpos & 63] = z;
    } else {
      const float* hsrc = Hglob + ((size_t)(g * 2 + ((t - 1) & 1)) * BPG + sb) * DD + kpos;
      f32x4 hv = ld_mall128(hsrc);
      float4 hq; hq.x = hv.x; hq.y = hv.y; hq.z = hv.z; hq.w = hv.w;
      *(float4*)&in_buf[sb][8 + (kpos >> 6)][kpos & 63] = hq;
    }
    __syncthreads();   // B: h staged

    // --- h-part dots + combine with x-part ---
    float r0[BPG], r1[BPG];
    #pragma unroll
    for (int b = 0; b < BPG; ++b) {
      const float4* vp = (const float4*)&in_buf[b][8 + (kc >> 1)][(kc & 1) * 32];
      float4 a0 = {0,0,0,0}, a1 = {0,0,0,0};
      #pragma unroll
      for (int q = 0; q < 8; ++q) {
        float4 vv = vp[q];
        a0.x += vv.x * w0h[q].x; a0.y += vv.y * w0h[q].y;
        a0.z += vv.z * w0h[q].z; a0.w += vv.w * w0h[q].w;
        a1.x += vv.x * w1h[q].x; a1.y += vv.y * w1h[q].y;
        a1.z += vv.z * w1h[q].z; a1.w += vv.w * w1h[q].w;
      }
      r0[b] = rx0[b] + (a0.x + a0.y) + (a0.z + a0.w);
      r1[b] = rx1[b] + (a1.x + a1.y) + (a1.z + a1.w);
    }
    // reduce across the 16 kc lanes; all 4 batches interleaved for ILP
    #pragma unroll
    for (int m = 1; m < 16; m <<= 1) {
      #pragma unroll
      for (int b = 0; b < BPG; ++b) {
        r0[b] += __shfl_xor(r0[b], m, 64);
        r1[b] += __shfl_xor(r1[b], m, 64);
      }
    }

    // --- in-wave cell update: lanes tid^16 hold (f,o) for this lane's (i,g) ---
    float* hd = Hglob + (size_t)(g * 2 + (t & 1)) * BPG * DD + u0 + v;
    #pragma unroll
    for (int b = 0; b < BPG; ++b) {
      float f_in = __shfl_xor(r0[b], 16, 64);
      float o_in = __shfl_xor(r1[b], 16, 64);
      float ig = sigm(r0[b] + b_i);
      float fg = sigm(f_in + b_f);
      float gg = tanh_fast(r1[b] + b_g);
      float og = sigm(o_in + b_o);
      float c  = fg * c_st[b] + ig * gg;
      c_st[b] = c;
      float h  = og * tanh_fast(c);
      if ((tid & 31) == 0)   // owning lane for unit v (gl==0, kc==0)
        st_mall32((unsigned*)(hd + b * DD), __float_as_uint(h));
    }
    // C: compiler drains vmcnt(0) per wave before s_barrier -> every wave's
    // h-stores have reached the coherence point when tid 0 publishes.
    __syncthreads();
    if (tid == 0) st_mall32(&flags[g * GS + s], (unsigned)(t + 1));

    // --- out-write h(t-1) AFTER publish (off the inter-block critical path).
    // Rows 8-15 stay valid until h-stage(t+1), which is behind A+Bp(t+1). ---
    if (t > 0 && tid < ROWS) {
      int flat = s * 64 + tid;           // partition of group's [BPG][DD]
      int ob = flat >> 9, okp = flat & 511;
      out[((size_t)(gb0 + ob) * TT + (t - 1)) * DD + okp] =
          in_buf[ob][8 + (okp >> 6)][okp & 63];
    }
  }

  // --- emit final timestep h(T-1) straight from Hglob ---
  if (tid < GS) {
    int guard = 0;
    while (ld_mall32(&flags[g * GS + tid]) < (unsigned)TT) {
      if (++guard > (1 << 24)) break;
      __builtin_amdgcn_s_sleep(1);
    }
  }
  __syncthreads();
  if (tid < ROWS) {
    int flat = s * 64 + tid;
    int ob = flat >> 9, okp = flat & 511;
    const unsigned* hsrc = (const unsigned*)Hglob
        + ((size_t)(g * 2 + ((TT - 1) & 1)) * BPG + ob) * DD + okp;
    out[((size_t)(gb0 + ob) * TT + (TT - 1)) * DD + okp] =
        __uint_as_float(ld_mall32(hsrc));
  }
}

extern "C" void kernel_launch(void* const* d_in, const int* in_sizes, int n_in,
                              void* d_out, int out_size, void* d_ws, size_t ws_size,
                              hipStream_t stream) {
  const float* x   = (const float*)d_in[0];
  const float* Wih = (const float*)d_in[1];
  const float* Whh = (const float*)d_in[2];
  const float* bih = (const float*)d_in[3];
  const float* bhh = (const float*)d_in[4];
  float* out = (float*)d_out;

  // ws layout: Hglob [8][2][4][512] f32 = 128 KB, then flags [8][32] u32 = 1 KB
  float* Hglob = (float*)d_ws;
  unsigned* flags = (unsigned*)((char*)d_ws + (size_t)GB * 2 * BPG * DD * sizeof(float));

  // ws is poisoned before every call: zero the flags before the kernel polls them.
  hipMemsetAsync(flags, 0, (size_t)GB * GS * sizeof(unsigned), stream);

  lstm_persistent<<<dim3(NBLK), dim3(NTHR), 0, stream>>>(x, Wih, Whh, bih, bhh,
                                                         out, Hglob, flags);
}